// Round 1
// baseline (128.849 us; speedup 1.0000x reference)
//
#include <hip/hip_runtime.h>
#include <hip/hip_bf16.h>

// LearnableDiffusionContrastiveLoss on MI355X.
// Key algebra: l2norm(dm_normalized @ z) == l2norm(dm @ z) since row scaling
// is positive -> skip the 10-step normalization entirely.
// positive = dm @ z via bf16 MFMA (fp32 accum), K-split partials; loss fused.

typedef float f32x4 __attribute__((ext_vector_type(4)));
typedef short s16x8 __attribute__((ext_vector_type(8)));

#define NN 8192
#define DFF 256
#define NNEG 10

__device__ __forceinline__ unsigned short f2bf(float x) {
  return __builtin_bit_cast(unsigned short, __float2bfloat16(x));
}

__device__ __forceinline__ void gload_lds16(const void* g, void* l) {
  __builtin_amdgcn_global_load_lds(
      (const __attribute__((address_space(1))) void*)(void*)g,
      (__attribute__((address_space(3))) void*)l, 16, 0, 0);
}

__device__ __forceinline__ float dot4(float4 a, float4 b) {
  return a.x * b.x + a.y * b.y + a.z * b.z + a.w * b.w;
}

// ---- z [8192][256] f32  ->  zT bf16 [256][8192] ------------------------------
__global__ void k_transpose(const float* __restrict__ z,
                            unsigned short* __restrict__ zT) {
  __shared__ float tile[64][65];
  const int bx = blockIdx.x;  // row tile 0..127
  const int by = blockIdx.y;  // col tile 0..3
  const int t = threadIdx.x;
  const int lc = t & 63, lq = t >> 6;  // 0..3
#pragma unroll
  for (int p = 0; p < 16; ++p) {
    const int lr = lq * 16 + p;
    tile[lr][lc] = z[(size_t)(bx * 64 + lr) * DFF + by * 64 + lc];
  }
  __syncthreads();
#pragma unroll
  for (int p = 0; p < 16; ++p) {
    const int tc = lq * 16 + p;  // col of z == row of zT
    zT[(size_t)(by * 64 + tc) * NN + bx * 64 + lc] = f2bf(tile[lc][tc]);
  }
}

// ---- normalized negatives: negn[10][256] -------------------------------------
__global__ void k_neg(const float* __restrict__ z, const int* __restrict__ neg_idx,
                      float* __restrict__ negn) {
  const int l = threadIdx.x;  // 64
#pragma unroll
  for (int k = 0; k < NNEG; ++k) {
    const int idx = neg_idx[k];
    float4 v = *(const float4*)(z + (size_t)idx * DFF + l * 4);
    float ss = dot4(v, v);
#pragma unroll
    for (int off = 32; off > 0; off >>= 1) ss += __shfl_xor(ss, off);
    const float s = 1.0f / fmaxf(sqrtf(ss), 1e-12f);
    float4 o;
    o.x = v.x * s; o.y = v.y * s; o.z = v.z * s; o.w = v.w * s;
    *(float4*)(negn + k * DFF + l * 4) = o;
  }
}

// ---- GEMM: part[ks] += dm[m,:](bf16) @ z (as zT bf16), per-K-split partials --
// BM=64, BN=256 (full), BK=64. 4 waves, each 64 rows x 64 cols (4x4 16x16 frags).
// LDS XOR swizzle: elem_in_row ^= (row&7)<<3  (byte ^= (row&7)<<4).
__global__ __launch_bounds__(256, 2) void k_gemm(const float* __restrict__ dm,
                                                 const unsigned short* __restrict__ zT,
                                                 float* __restrict__ part, int KS) {
  __shared__ unsigned short sA[64 * 64];   // 8 KB
  __shared__ unsigned short sB[256 * 64];  // 32 KB
  const int bx = blockIdx.x;
  const int mtile = bx & 127;
  const int ks = bx >> 7;
  const int klen = NN / KS;
  const int k0 = ks * klen;
  const int steps = klen / 64;
  const int tid = threadIdx.x;
  const int w = tid >> 6;
  const int l = tid & 63;
  const int m0 = mtile * 64;

  f32x4 acc[4][4] = {};

  const int ar = tid >> 4;        // 0..15 (row within 16-row pass group)
  const int ac = (tid & 15) * 4;  // f32 elem within 64-wide k chunk

  // B staging source pattern: linear LDS dest + inverse-swizzled global source
  const int rq = l >> 3;             // 0..7 row within 8-row issue group
  const int bsw = (l & 7) * 16;      // byte slot this lane fills in the 128B row
  const int blog = bsw ^ (rq << 4);  // logical byte in zT row ((row&7)==rq here)

  for (int kt = 0; kt < steps; ++kt) {
    const int kb = k0 + kt * 64;
    // stage A: reg-staged f32 -> bf16, swizzled ds_write
#pragma unroll
    for (int p = 0; p < 4; ++p) {
      const int r = p * 16 + ar;
      const float4 v = *(const float4*)(dm + (size_t)(m0 + r) * NN + kb + ac);
      ushort4 h;
      h.x = f2bf(v.x); h.y = f2bf(v.y); h.z = f2bf(v.z); h.w = f2bf(v.w);
      *(ushort4*)&sA[r * 64 + (ac ^ ((r & 7) << 3))] = h;
    }
    // stage B: global_load_lds dwordx4, wave w covers rows 64w..64w+63
    {
      const char* srcbase = (const char*)zT + (size_t)kb * 2 + blog;
#pragma unroll
      for (int q = 0; q < 8; ++q) {
        const int rn = w * 64 + q * 8 + rq;
        gload_lds16(srcbase + (size_t)rn * (NN * 2),
                    (char*)sB + (w * 64 + q * 8) * 128);
      }
    }
    __syncthreads();
#pragma unroll
    for (int kc = 0; kc < 2; ++kc) {
      const int e = kc * 32 + (l >> 4) * 8;
      s16x8 af[4], bfr[4];
#pragma unroll
      for (int mi = 0; mi < 4; ++mi) {
        const int r = mi * 16 + (l & 15);
        af[mi] = *(const s16x8*)&sA[r * 64 + (e ^ ((r & 7) << 3))];
      }
#pragma unroll
      for (int nj = 0; nj < 4; ++nj) {
        const int rn = w * 64 + nj * 16 + (l & 15);
        bfr[nj] = *(const s16x8*)&sB[rn * 64 + (e ^ ((rn & 7) << 3))];
      }
#pragma unroll
      for (int mi = 0; mi < 4; ++mi)
#pragma unroll
        for (int nj = 0; nj < 4; ++nj)
          acc[mi][nj] = __builtin_amdgcn_mfma_f32_16x16x32_bf16(
              af[mi], bfr[nj], acc[mi][nj], 0, 0, 0);
    }
    __syncthreads();
  }
  // epilogue: C/D layout col=lane&15, row=(lane>>4)*4+reg  [verified m89/m91]
  float* cb = part + (size_t)ks * NN * DFF;
#pragma unroll
  for (int mi = 0; mi < 4; ++mi)
#pragma unroll
    for (int nj = 0; nj < 4; ++nj) {
      const int col = w * 64 + nj * 16 + (l & 15);
      const int row0 = m0 + mi * 16 + (l >> 4) * 4;
#pragma unroll
      for (int r = 0; r < 4; ++r)
        cb[(size_t)(row0 + r) * DFF + col] = acc[mi][nj][r];
    }
}

// ---- fused loss: sums K-split partials, norms, 10 neg dots, log-sum-exp ------
__global__ __launch_bounds__(256) void k_loss(const float* __restrict__ z,
                                              const float* __restrict__ part,
                                              const float* __restrict__ negn,
                                              float* __restrict__ lpart, int KS) {
  __shared__ float sneg[NNEG * DFF];
  __shared__ float swsum[4];
  const int t = threadIdx.x;
  for (int j = t; j < NNEG * DFF; j += 256) sneg[j] = negn[j];
  __syncthreads();
  const int w = t >> 6, l = t & 63;
  const int gw = blockIdx.x * 4 + w;  // 0..1023, 8 rows each
  float lsum = 0.f;
  for (int rr = 0; rr < 8; ++rr) {
    const int i = gw * 8 + rr;
    const float4 a = *(const float4*)(z + (size_t)i * DFF + l * 4);
    float4 p; p.x = 0.f; p.y = 0.f; p.z = 0.f; p.w = 0.f;
    for (int ksp = 0; ksp < KS; ++ksp) {
      const float4 q = *(const float4*)(part + ((size_t)ksp * NN + i) * DFF + l * 4);
      p.x += q.x; p.y += q.y; p.z += q.z; p.w += q.w;
    }
    float vals[13];
    vals[0] = dot4(a, a);
    vals[1] = dot4(p, p);
    vals[2] = dot4(a, p);
#pragma unroll
    for (int k = 0; k < NNEG; ++k) {
      const float4 nv = *(const float4*)&sneg[k * DFF + l * 4];
      vals[3 + k] = dot4(a, nv);
    }
#pragma unroll
    for (int off = 32; off > 0; off >>= 1)
#pragma unroll
      for (int j = 0; j < 13; ++j) vals[j] += __shfl_xor(vals[j], off);
    const float na = fmaxf(sqrtf(vals[0]), 1e-12f);
    const float npp = fmaxf(sqrtf(vals[1]), 1e-12f);
    const float ps = vals[2] / (na * npp) * 5.0f;  // 1/TEMP
    float S = 0.f;
#pragma unroll
    for (int k = 0; k < NNEG; ++k) S += expf(vals[3 + k] / na * 5.0f);
    lsum += logf(expf(ps) + S) - ps;
  }
  if (l == 0) swsum[w] = lsum;
  __syncthreads();
  if (t == 0) lpart[blockIdx.x] = swsum[0] + swsum[1] + swsum[2] + swsum[3];
}

__global__ void k_final(const float* __restrict__ lpart, float* __restrict__ out) {
  const int t = threadIdx.x;  // 64
  float v = lpart[t] + lpart[t + 64] + lpart[t + 128] + lpart[t + 192];
#pragma unroll
  for (int off = 32; off > 0; off >>= 1) v += __shfl_xor(v, off);
  if (t == 0) out[0] = v * (1.0f / (float)NN);
}

extern "C" void kernel_launch(void* const* d_in, const int* in_sizes, int n_in,
                              void* d_out, int out_size, void* d_ws, size_t ws_size,
                              hipStream_t stream) {
  const float* z = (const float*)d_in[0];
  const float* dm = (const float*)d_in[1];
  // d_in[2] edge_index, d_in[3] reliable_negatives: unused by the forward pass
  const int* neg_idx = (const int*)d_in[4];
  float* out = (float*)d_out;

  // workspace: zT (4MB) | partials (KS*8MB) | negn (10KB) | lpart (1KB)
  auto need = [](size_t ks) {
    return (size_t)4 * 1024 * 1024 + ks * (size_t)NN * DFF * 4 + 10240 + 1024;
  };
  int KS = 4;
  if (ws_size < need(4)) KS = (ws_size >= need(2)) ? 2 : 1;

  char* ws = (char*)d_ws;
  unsigned short* zT = (unsigned short*)ws;
  float* part = (float*)(ws + (size_t)4 * 1024 * 1024);
  float* negn = (float*)(ws + (size_t)4 * 1024 * 1024 + (size_t)KS * NN * DFF * 4);
  float* lpart = (float*)((char*)negn + NNEG * DFF * 4);

  k_transpose<<<dim3(128, 4), 256, 0, stream>>>(z, zT);
  k_neg<<<1, 64, 0, stream>>>(z, neg_idx, negn);
  k_gemm<<<128 * KS, 256, 0, stream>>>(dm, zT, part, KS);
  k_loss<<<256, 256, 0, stream>>>(z, part, negn, lpart, KS);
  k_final<<<1, 64, 0, stream>>>(lpart, out);
}

// Round 2
// 124.671 us; speedup vs baseline: 1.0335x; 1.0335x over previous
//
#include <hip/hip_runtime.h>
#include <hip/hip_bf16.h>

// LearnableDiffusionContrastiveLoss on MI355X.
// Algebra: l2norm(dm_normalized @ z) == l2norm(dm @ z) (positive row scaling
// cancels) -> skip the 10-step normalization entirely.
// positive = dm @ z via bf16 MFMA (fp32 accum), K-split partials; loss fused.
// R2: double-buffered LDS 2-phase pipeline (stage t+1 before compute t,
//     single barrier/step); k_neg folded into k_loss.

typedef float f32x4 __attribute__((ext_vector_type(4)));
typedef short s16x8 __attribute__((ext_vector_type(8)));

#define NN 8192
#define DFF 256
#define NNEG 10

__device__ __forceinline__ unsigned short f2bf(float x) {
  return __builtin_bit_cast(unsigned short, __float2bfloat16(x));
}

__device__ __forceinline__ void gload_lds16(const void* g, void* l) {
  __builtin_amdgcn_global_load_lds(
      (const __attribute__((address_space(1))) void*)(void*)g,
      (__attribute__((address_space(3))) void*)l, 16, 0, 0);
}

__device__ __forceinline__ float dot4(float4 a, float4 b) {
  return a.x * b.x + a.y * b.y + a.z * b.z + a.w * b.w;
}

// ---- z [8192][256] f32  ->  zT bf16 [256][8192] ------------------------------
__global__ void k_transpose(const float* __restrict__ z,
                            unsigned short* __restrict__ zT) {
  __shared__ float tile[64][65];
  const int bx = blockIdx.x;  // row tile 0..127
  const int by = blockIdx.y;  // col tile 0..3
  const int t = threadIdx.x;
  const int lc = t & 63, lq = t >> 6;  // 0..3
#pragma unroll
  for (int p = 0; p < 16; ++p) {
    const int lr = lq * 16 + p;
    tile[lr][lc] = z[(size_t)(bx * 64 + lr) * DFF + by * 64 + lc];
  }
  __syncthreads();
#pragma unroll
  for (int p = 0; p < 16; ++p) {
    const int tc = lq * 16 + p;  // col of z == row of zT
    zT[(size_t)(by * 64 + tc) * NN + bx * 64 + lc] = f2bf(tile[lc][tc]);
  }
}

// ---- GEMM: part[ks] = dm[mtile,:klen](bf16) @ z (as zT bf16) -----------------
// BM=64, BN=256 (full), BK=64. 4 waves, each 64 rows x 64 cols (4x4 16x16 frags).
// LDS XOR swizzle: elem_in_row ^= (row&7)<<3  (byte ^= (row&7)<<4).
// 2-phase pipeline: issue stage(t+1) -> compute(t) -> writeA(t+1) -> barrier.
__global__ __launch_bounds__(256, 2) void k_gemm(const float* __restrict__ dm,
                                                 const unsigned short* __restrict__ zT,
                                                 float* __restrict__ part, int KS) {
  __shared__ unsigned short sA[2][64 * 64];   // 2 x 8 KB
  __shared__ unsigned short sB[2][256 * 64];  // 2 x 32 KB
  const int bx = blockIdx.x;
  const int mtile = bx & 127;
  const int ks = bx >> 7;
  const int klen = NN / KS;
  const int k0 = ks * klen;
  const int steps = klen / 64;
  const int tid = threadIdx.x;
  const int w = tid >> 6;
  const int l = tid & 63;
  const int m0 = mtile * 64;

  f32x4 acc[4][4] = {};

  const int ar = tid >> 4;        // 0..15 (row within 16-row pass group)
  const int ac = (tid & 15) * 4;  // f32 elem within 64-wide k chunk

  // B staging: linear LDS dest + inverse-swizzled global source
  const int rq = l >> 3;             // 0..7 row within 8-row issue group
  const int bsw = (l & 7) * 16;      // byte slot this lane fills in the 128B row
  const int blog = bsw ^ (rq << 4);  // logical byte in zT row ((row&7)==rq here)

  float4 areg[4];

#define LOAD_A(kt)                                                             \
  _Pragma("unroll") for (int p = 0; p < 4; ++p) areg[p] =                      \
      *(const float4*)(dm + (size_t)(m0 + p * 16 + ar) * NN + k0 + (kt)*64 + ac);

#define WRITE_A(buf)                                                           \
  _Pragma("unroll") for (int p = 0; p < 4; ++p) {                              \
    const int r = p * 16 + ar;                                                 \
    ushort4 h;                                                                 \
    h.x = f2bf(areg[p].x); h.y = f2bf(areg[p].y);                              \
    h.z = f2bf(areg[p].z); h.w = f2bf(areg[p].w);                              \
    *(ushort4*)&sA[buf][r * 64 + (ac ^ ((r & 7) << 3))] = h;                   \
  }

#define STAGE_B(kt, buf)                                                       \
  {                                                                            \
    const char* srcbase = (const char*)zT + (size_t)(k0 + (kt)*64) * 2 + blog; \
    _Pragma("unroll") for (int q = 0; q < 8; ++q) {                            \
      gload_lds16(srcbase + (size_t)(w * 64 + q * 8 + rq) * (NN * 2),          \
                  (char*)sB[buf] + (w * 64 + q * 8) * 128);                    \
    }                                                                          \
  }

  // prologue: fill buffer 0
  STAGE_B(0, 0);
  LOAD_A(0);
  WRITE_A(0);      // compiler auto-waits areg
  __syncthreads(); // drains vmcnt (B lds) + lgkm (A writes)

  for (int kt = 0; kt < steps; ++kt) {
    const int cur = kt & 1, nxt = cur ^ 1;
    if (kt + 1 < steps) {
      LOAD_A(kt + 1);
      STAGE_B(kt + 1, nxt);
    }
    // compute from buf[cur]
#pragma unroll
    for (int kc = 0; kc < 2; ++kc) {
      const int e = kc * 32 + (l >> 4) * 8;
      s16x8 af[4], bfr[4];
#pragma unroll
      for (int mi = 0; mi < 4; ++mi) {
        const int r = mi * 16 + (l & 15);
        af[mi] = *(const s16x8*)&sA[cur][r * 64 + (e ^ ((r & 7) << 3))];
      }
#pragma unroll
      for (int nj = 0; nj < 4; ++nj) {
        const int rn = w * 64 + nj * 16 + (l & 15);
        bfr[nj] = *(const s16x8*)&sB[cur][rn * 64 + (e ^ ((rn & 7) << 3))];
      }
#pragma unroll
      for (int mi = 0; mi < 4; ++mi)
#pragma unroll
        for (int nj = 0; nj < 4; ++nj)
          acc[mi][nj] = __builtin_amdgcn_mfma_f32_16x16x32_bf16(
              af[mi], bfr[nj], acc[mi][nj], 0, 0, 0);
    }
    if (kt + 1 < steps) {
      WRITE_A(nxt);  // sA[nxt] last read at kt-1; safe after kt-1's barrier
    }
    __syncthreads();  // built-in vmcnt(0)+lgkmcnt(0) drain; loads had whole
                      // compute phase to land
  }

  // epilogue: C/D layout col=lane&15, row=(lane>>4)*4+reg  [verified m89/m91]
  float* cb = part + (size_t)ks * NN * DFF;
#pragma unroll
  for (int mi = 0; mi < 4; ++mi)
#pragma unroll
    for (int nj = 0; nj < 4; ++nj) {
      const int col = w * 64 + nj * 16 + (l & 15);
      const int row0 = m0 + mi * 16 + (l >> 4) * 4;
#pragma unroll
      for (int r = 0; r < 4; ++r)
        cb[(size_t)(row0 + r) * DFF + col] = acc[mi][nj][r];
    }
#undef LOAD_A
#undef WRITE_A
#undef STAGE_B
}

// ---- fused loss: neg norms, K-split partial sum, norms, log-sum-exp ----------
__global__ __launch_bounds__(256) void k_loss(const float* __restrict__ z,
                                              const float* __restrict__ part,
                                              const int* __restrict__ neg_idx,
                                              float* __restrict__ lpart, int KS) {
  __shared__ float sneg[NNEG * DFF];
  __shared__ float swsum[4];
  const int t = threadIdx.x;
  const int w = t >> 6, l = t & 63;
  // normalized negatives (redundant per block; 10 KB)
  for (int k = w; k < NNEG; k += 4) {
    const int idx = neg_idx[k];
    float4 v = *(const float4*)(z + (size_t)idx * DFF + l * 4);
    float ss = dot4(v, v);
#pragma unroll
    for (int off = 32; off > 0; off >>= 1) ss += __shfl_xor(ss, off);
    const float s = 1.0f / fmaxf(sqrtf(ss), 1e-12f);
    float4 o;
    o.x = v.x * s; o.y = v.y * s; o.z = v.z * s; o.w = v.w * s;
    *(float4*)&sneg[k * DFF + l * 4] = o;
  }
  __syncthreads();
  const int gw = blockIdx.x * 4 + w;  // 0..1023, 8 rows each
  float lsum = 0.f;
  for (int rr = 0; rr < 8; ++rr) {
    const int i = gw * 8 + rr;
    const float4 a = *(const float4*)(z + (size_t)i * DFF + l * 4);
    float4 p; p.x = 0.f; p.y = 0.f; p.z = 0.f; p.w = 0.f;
    for (int ksp = 0; ksp < KS; ++ksp) {
      const float4 q = *(const float4*)(part + ((size_t)ksp * NN + i) * DFF + l * 4);
      p.x += q.x; p.y += q.y; p.z += q.z; p.w += q.w;
    }
    float vals[13];
    vals[0] = dot4(a, a);
    vals[1] = dot4(p, p);
    vals[2] = dot4(a, p);
#pragma unroll
    for (int k = 0; k < NNEG; ++k) {
      const float4 nv = *(const float4*)&sneg[k * DFF + l * 4];
      vals[3 + k] = dot4(a, nv);
    }
#pragma unroll
    for (int off = 32; off > 0; off >>= 1)
#pragma unroll
      for (int j = 0; j < 13; ++j) vals[j] += __shfl_xor(vals[j], off);
    const float na = fmaxf(sqrtf(vals[0]), 1e-12f);
    const float npp = fmaxf(sqrtf(vals[1]), 1e-12f);
    const float ps = vals[2] / (na * npp) * 5.0f;  // 1/TEMP
    float S = 0.f;
#pragma unroll
    for (int k = 0; k < NNEG; ++k) S += expf(vals[3 + k] / na * 5.0f);
    lsum += logf(expf(ps) + S) - ps;
  }
  if (l == 0) swsum[w] = lsum;
  __syncthreads();
  if (t == 0) lpart[blockIdx.x] = swsum[0] + swsum[1] + swsum[2] + swsum[3];
}

__global__ void k_final(const float* __restrict__ lpart, float* __restrict__ out) {
  const int t = threadIdx.x;  // 64
  float v = lpart[t] + lpart[t + 64] + lpart[t + 128] + lpart[t + 192];
#pragma unroll
  for (int off = 32; off > 0; off >>= 1) v += __shfl_xor(v, off);
  if (t == 0) out[0] = v * (1.0f / (float)NN);
}

extern "C" void kernel_launch(void* const* d_in, const int* in_sizes, int n_in,
                              void* d_out, int out_size, void* d_ws, size_t ws_size,
                              hipStream_t stream) {
  const float* z = (const float*)d_in[0];
  const float* dm = (const float*)d_in[1];
  // d_in[2] edge_index, d_in[3] reliable_negatives: unused by the forward pass
  const int* neg_idx = (const int*)d_in[4];
  float* out = (float*)d_out;

  // workspace: zT (4MB) | partials (KS*8MB) | lpart (1KB)
  auto need = [](size_t ks) {
    return (size_t)4 * 1024 * 1024 + ks * (size_t)NN * DFF * 4 + 1024;
  };
  int KS = 4;
  if (ws_size < need(4)) KS = (ws_size >= need(2)) ? 2 : 1;

  char* ws = (char*)d_ws;
  unsigned short* zT = (unsigned short*)ws;
  float* part = (float*)(ws + (size_t)4 * 1024 * 1024);
  float* lpart = (float*)(ws + (size_t)4 * 1024 * 1024 + (size_t)KS * NN * DFF * 4);

  k_transpose<<<dim3(128, 4), 256, 0, stream>>>(z, zT);
  k_gemm<<<128 * KS, 256, 0, stream>>>(dm, zT, part, KS);
  k_loss<<<256, 256, 0, stream>>>(z, part, neg_idx, lpart, KS);
  k_final<<<1, 64, 0, stream>>>(lpart, out);
}